// Round 10
// baseline (890.999 us; speedup 1.0000x reference)
//
#include <hip/hip_runtime.h>
#include <hip/hip_bf16.h>

using bf16 = __hip_bfloat16;
typedef __attribute__((ext_vector_type(8))) short short8;
typedef __attribute__((ext_vector_type(4))) float f32x4;

// ---------------- helpers ----------------
__device__ __forceinline__ float tof(float v) { return v; }
__device__ __forceinline__ float tof(bf16 v) { return __bfloat162float(v); }
__device__ __forceinline__ float s2f(short s) {
    return __uint_as_float(((unsigned)(unsigned short)s) << 16);
}
__device__ __forceinline__ void storev(float* p, float v) { *p = v; }
__device__ __forceinline__ void storev(bf16* p, float v) { *p = __float2bfloat16(v); }
__device__ __forceinline__ short f2bf_bits(float v) {
    bf16 h = __float2bfloat16(v);
    return *(short*)&h;
}
__device__ __forceinline__ float wsum(float v) {
    #pragma unroll
    for (int o = 32; o > 0; o >>= 1) v += __shfl_xor(v, o);
    return v;
}
__device__ __forceinline__ float wmax(float v) {
    #pragma unroll
    for (int o = 32; o > 0; o >>= 1) v = fmaxf(v, __shfl_xor(v, o));
    return v;
}

// ---------------- weight preconvert: fp32 [Oreal][WLD] -> bf16 [Oalloc][KP], pad 0 ----
__global__ __launch_bounds__(256) void wconv_kernel(
    const float* __restrict__ src, bf16* __restrict__ dst,
    int Oreal, int Oalloc, int K, int KP, int WLD)
{
    const int idx = blockIdx.x * 256 + threadIdx.x;
    if (idx >= Oalloc * KP) return;
    const int o = idx / KP, k = idx % KP;
    float v = (o < Oreal && k < K) ? src[(size_t)o * WLD + k] : 0.f;
    dst[idx] = __float2bfloat16(v);
}

// ---------------- LayerNorm C=192: fp32 [b][192][N] -> bf16 [b][n][192] ----------------
__global__ __launch_bounds__(256) void ln_t_kernel(
    const float* __restrict__ X, const float* __restrict__ w,
    const float* __restrict__ bias, bf16* __restrict__ Y, int N)
{
    const int wv = threadIdx.x >> 6, ln_ = threadIdx.x & 63;
    const int p = blockIdx.x * 128 + wv * 32 + (ln_ & 31);   // flat pixel in B*N
    const int b = p >> 14, n = p & 16383;                    // N = 16384
    const int c0 = (ln_ >> 5) * 96;
    const float* xp = X + ((size_t)b * 192 + c0) * N + n;
    float s = 0.f, s2 = 0.f;
    #pragma unroll
    for (int c = 0; c < 96; c++) { float v = xp[(size_t)c * N]; s += v; s2 += v * v; }
    s += __shfl_xor(s, 32);
    s2 += __shfl_xor(s2, 32);
    const float mean = s * (1.f / 192.f);
    const float rstd = rsqrtf(s2 * (1.f / 192.f) - mean * mean + 1e-5f);
    bf16* yp = Y + ((size_t)(b * 16384 + n)) * 192 + c0;
    #pragma unroll
    for (int c = 0; c < 96; c += 2) {
        float v0 = (xp[(size_t)c * N] - mean) * rstd * w[c0 + c] + bias[c0 + c];
        float v1 = (xp[(size_t)(c + 1) * N] - mean) * rstd * w[c0 + c + 1] + bias[c0 + c + 1];
        unsigned u = (unsigned)(unsigned short)f2bf_bits(v0) |
                     ((unsigned)(unsigned short)f2bf_bits(v1) << 16);
        *(unsigned*)(yp + c) = u;
    }
}

// ---- weights-in-registers MFMA GEMM, XCD-swizzled: Y[b][o][n] = W[o][:].X[b][n][:] ----
// NSTEP=64: single step per block -> all B-fragment loads in flight, stores at end only.
template<int K, int NSTEP, typename YT, bool RESID>
__global__ __launch_bounds__(256) void wreg_gemm_kernel(
    const bf16* __restrict__ Wb, const bf16* __restrict__ X,
    const float* __restrict__ Rsd, YT* __restrict__ Y,
    int O, int KS, int NROW)
{
    constexpr int KST = K / 32;
    // bijective XCD swizzle: each XCD gets a contiguous work chunk, o fastest
    const int OT = gridDim.x, NT = gridDim.y;
    const int orig = blockIdx.x + OT * (blockIdx.y + NT * blockIdx.z);
    const int total = OT * NT * gridDim.z;
    const int qq = total >> 3, rr = total & 7;
    const int xcd = orig & 7, loc = orig >> 3;
    const int nw = (xcd < rr ? xcd * (qq + 1) : rr * (qq + 1) + (xcd - rr) * qq) + loc;
    const int o0 = (nw % OT) * 64;
    const int nbase = ((nw / OT) % NT) * NSTEP;
    const int b = nw / (OT * NT);

    const int wave = threadIdx.x >> 6, lane = threadIdx.x & 63;
    const int arow = lane & 15, kg = lane >> 4;

    short8 wf[KST];
    {
        const bf16* wp = Wb + (size_t)(o0 + wave * 16 + arow) * K + kg * 8;
        #pragma unroll
        for (int ks = 0; ks < KST; ks++) wf[ks] = *(const short8*)(wp + ks * 32);
    }
    const bf16* Xb = X + ((size_t)b * NROW + nbase) * KS;

    #pragma unroll 1
    for (int nt = 0; nt < NSTEP; nt += 64) {
        f32x4 acc[4];
        #pragma unroll
        for (int s = 0; s < 4; s++) acc[s] = (f32x4){0.f, 0.f, 0.f, 0.f};
        #pragma unroll
        for (int s = 0; s < 4; s++) {
            const bf16* xp = Xb + (size_t)(nt + s * 16 + arow) * KS + kg * 8;
            #pragma unroll
            for (int ks = 0; ks < KST; ks++) {
                short8 bfr = *(const short8*)(xp + ks * 32);
                acc[s] = __builtin_amdgcn_mfma_f32_16x16x32_bf16(wf[ks], bfr, acc[s], 0, 0, 0);
            }
        }
        #pragma unroll
        for (int s = 0; s < 4; s++) {
            #pragma unroll
            for (int r = 0; r < 4; r++) {
                const int o = o0 + wave * 16 + kg * 4 + r;
                if (o < O) {
                    const size_t off = ((size_t)b * O + o) * NROW + nbase + nt + s * 16 + arow;
                    float v = acc[s][r];
                    if (RESID) v += Rsd[off];
                    storev(&Y[off], v);
                }
            }
        }
    }
}

// -------- tiled depthwise 3x3 (bf16 planes), vector LDS reads: 1 ch x 16 y x 128 x ----
__global__ __launch_bounds__(256) void dwconv3_tile_kernel(
    const bf16* __restrict__ X, const float* __restrict__ Wd, bf16* __restrict__ Y,
    int CH)
{
    __shared__ short sm[18][144];   // x0 at col 8; zero halos at 7 and 136
    const int b = blockIdx.z, ch = blockIdx.y;
    const int y0 = blockIdx.x * 16;
    const int tid = threadIdx.x;
    const size_t base = ((size_t)b * CH + ch) * 16384;

    for (int idx = tid; idx < 288; idx += 256) {
        const int r = idx >> 4, xc = idx & 15;
        const int yy = y0 - 1 + r;
        short8 v = {0, 0, 0, 0, 0, 0, 0, 0};
        if (yy >= 0 && yy < 128) v = *(const short8*)(X + base + yy * 128 + xc * 8);
        *(short8*)&sm[r][8 + xc * 8] = v;
    }
    if (tid < 18) { sm[tid][7] = 0; sm[tid][136] = 0; }
    __syncthreads();

    float wv[9];
    #pragma unroll
    for (int i = 0; i < 9; i++) wv[i] = Wd[ch * 9 + i];

    const int ty = tid >> 4, xg = tid & 15;
    float a[8] = {0.f, 0.f, 0.f, 0.f, 0.f, 0.f, 0.f, 0.f};
    #pragma unroll
    for (int dy = 0; dy < 3; dy++) {
        const short* row = &sm[ty + dy][xg * 8];
        short8 pv = *(const short8*)row;
        short8 cv = *(const short8*)(row + 8);
        short8 nv = *(const short8*)(row + 16);
        float u[10];
        u[0] = s2f(((short*)&pv)[7]);
        #pragma unroll
        for (int j = 0; j < 8; j++) u[j + 1] = s2f(((short*)&cv)[j]);
        u[9] = s2f(((short*)&nv)[0]);
        const float wa = wv[dy * 3], wb = wv[dy * 3 + 1], wc = wv[dy * 3 + 2];
        #pragma unroll
        for (int j = 0; j < 8; j++) a[j] += wa * u[j] + wb * u[j + 1] + wc * u[j + 2];
    }
    short8 ov;
    #pragma unroll
    for (int j = 0; j < 8; j++) ((short*)&ov)[j] = f2bf_bits(a[j]);
    *(short8*)(Y + base + (size_t)(y0 + ty) * 128 + xg * 8) = ov;
}

// ---- tiled fused dw3(f1)->gelu * dw3(f2) -> GT[b][n][512] ; 4 hc x 8 y x 128 x ------
// FB layout [b][1020][N]: f1 plane = hc, f2 plane = 510 + hc.
__global__ __launch_bounds__(256) void dwgelu_tile_kernel(
    const bf16* __restrict__ FB, const float* __restrict__ Wd, bf16* __restrict__ GT)
{
    __shared__ short s1[4][10][144];
    __shared__ short s2[4][10][144];
    __shared__ short ot[4][8][136];
    const int b = blockIdx.z;
    const int y0 = blockIdx.x * 8;
    const int hc0 = blockIdx.y * 4;
    const int tid = threadIdx.x;

    for (int idx = tid; idx < 640; idx += 256) {
        const int c = idx / 160, rem = idx % 160;
        const int r = rem >> 4, xc = rem & 15;
        const int yy = y0 - 1 + r;
        const int hc = hc0 + c;
        short8 v1 = {0,0,0,0,0,0,0,0}, v2 = v1;
        if (hc < 510 && yy >= 0 && yy < 128) {
            const size_t sp = (size_t)yy * 128 + xc * 8;
            v1 = *(const short8*)(FB + ((size_t)b * 1020 + hc) * 16384 + sp);
            v2 = *(const short8*)(FB + ((size_t)b * 1020 + 510 + hc) * 16384 + sp);
        }
        *(short8*)&s1[c][r][8 + xc * 8] = v1;
        *(short8*)&s2[c][r][8 + xc * 8] = v2;
    }
    if (tid < 40) {
        const int c = tid / 10, r = tid % 10;
        s1[c][r][7] = 0; s1[c][r][136] = 0;
        s2[c][r][7] = 0; s2[c][r][136] = 0;
    }
    __syncthreads();

    const int c = tid >> 6, y2 = (tid >> 4) & 3, xg = tid & 15;
    const int hc = hc0 + c;
    float w1[9], w2[9];
    #pragma unroll
    for (int i = 0; i < 9; i++) {
        w1[i] = (hc < 510) ? Wd[(size_t)hc * 9 + i] : 0.f;
        w2[i] = (hc < 510) ? Wd[(size_t)(510 + hc) * 9 + i] : 0.f;
    }
    #pragma unroll
    for (int t = 0; t < 2; t++) {
        const int yy = y2 * 2 + t;
        float d1[8] = {0.f,0.f,0.f,0.f,0.f,0.f,0.f,0.f};
        float d2[8] = {0.f,0.f,0.f,0.f,0.f,0.f,0.f,0.f};
        #pragma unroll
        for (int dy = 0; dy < 3; dy++) {
            const short* r1 = &s1[c][yy + dy][xg * 8];
            const short* r2 = &s2[c][yy + dy][xg * 8];
            short8 pa = *(const short8*)r1;
            short8 ca = *(const short8*)(r1 + 8);
            short8 na = *(const short8*)(r1 + 16);
            short8 pb = *(const short8*)r2;
            short8 cb = *(const short8*)(r2 + 8);
            short8 nb = *(const short8*)(r2 + 16);
            float u[10], v[10];
            u[0] = s2f(((short*)&pa)[7]);
            v[0] = s2f(((short*)&pb)[7]);
            #pragma unroll
            for (int j = 0; j < 8; j++) {
                u[j + 1] = s2f(((short*)&ca)[j]);
                v[j + 1] = s2f(((short*)&cb)[j]);
            }
            u[9] = s2f(((short*)&na)[0]);
            v[9] = s2f(((short*)&nb)[0]);
            const float a0 = w1[dy * 3], a1 = w1[dy * 3 + 1], a2 = w1[dy * 3 + 2];
            const float b0 = w2[dy * 3], b1 = w2[dy * 3 + 1], b2 = w2[dy * 3 + 2];
            #pragma unroll
            for (int j = 0; j < 8; j++) {
                d1[j] += a0 * u[j] + a1 * u[j + 1] + a2 * u[j + 2];
                d2[j] += b0 * v[j] + b1 * v[j + 1] + b2 * v[j + 2];
            }
        }
        short8 ov;
        #pragma unroll
        for (int j = 0; j < 8; j++) {
            float g = 0.5f * d1[j] * (1.f + erff(d1[j] * 0.70710678118654752f)) * d2[j];
            ((short*)&ov)[j] = f2bf_bits(g);
        }
        *(short8*)&ot[c][yy][xg * 8] = ov;
    }
    __syncthreads();
    for (int idx = tid; idx < 1024; idx += 256) {
        const int row = idx >> 7, col = idx & 127;
        short v0 = ot[0][row][col], v1 = ot[1][row][col];
        short v2 = ot[2][row][col], v3 = ot[3][row][col];
        uint2 pk;
        pk.x = (unsigned)(unsigned short)v0 | ((unsigned)(unsigned short)v1 << 16);
        pk.y = (unsigned)(unsigned short)v2 | ((unsigned)(unsigned short)v3 << 16);
        *(uint2*)(GT + ((size_t)b * 16384 + y0 * 128 + idx) * 512 + hc0) = pk;
    }
}

// ---------------- row L2 norms (bf16 rows of length N), short8 loads ----------------
__global__ __launch_bounds__(256) void rownorm_kernel(
    const bf16* __restrict__ X, float* __restrict__ inv, int N)
{
    const int row = blockIdx.x;
    const bf16* p = X + (size_t)row * N;
    float s = 0.f;
    for (int i = threadIdx.x * 8; i < N; i += 2048) {
        short8 v = *(const short8*)(p + i);
        #pragma unroll
        for (int j = 0; j < 8; j++) { float f = s2f(((short*)&v)[j]); s += f * f; }
    }
    s = wsum(s);
    __shared__ float red[4];
    if ((threadIdx.x & 63) == 0) red[threadIdx.x >> 6] = s;
    __syncthreads();
    if (threadIdx.x == 0) {
        float t = red[0] + red[1] + red[2] + red[3];
        inv[row] = 1.f / fmaxf(sqrtf(t), 1e-12f);
    }
}

// ------- gram via MFMA: attn_raw[bh][c][d] += sum_n q[c,n]*k[d,n] over n-chunk --------
__global__ __launch_bounds__(192) void gram_mfma_kernel(
    const bf16* __restrict__ Q, const bf16* __restrict__ K,
    float* __restrict__ attn_raw, int N)
{
    const int b = blockIdx.z, h = blockIdx.y;
    const int n0base = blockIdx.x * 512;
    const int wave = threadIdx.x >> 6, lane = threadIdx.x & 63;
    const int arow = lane & 15, kg = lane >> 4;
    const bf16* Qb = Q + ((size_t)b * 192 + h * 48 + wave * 16 + arow) * N;
    const bf16* Kb = K + ((size_t)b * 192 + h * 48) * N;

    f32x4 acc[3];
    #pragma unroll
    for (int di = 0; di < 3; di++) acc[di] = (f32x4){0.f, 0.f, 0.f, 0.f};

    #pragma unroll 4
    for (int t = 0; t < 16; t++) {
        const int n0 = n0base + t * 32 + kg * 8;
        short8 a = *(const short8*)(Qb + n0);
        #pragma unroll
        for (int di = 0; di < 3; di++) {
            short8 bfr = *(const short8*)(Kb + (size_t)(di * 16 + arow) * N + n0);
            acc[di] = __builtin_amdgcn_mfma_f32_16x16x32_bf16(a, bfr, acc[di], 0, 0, 0);
        }
    }
    float* A = attn_raw + (size_t)(b * 4 + h) * 2304;
    const int c = wave * 16 + kg * 4;
    #pragma unroll
    for (int di = 0; di < 3; di++)
        #pragma unroll
        for (int r = 0; r < 4; r++)
            atomicAdd(&A[(c + r) * 48 + di * 16 + arow], acc[di][r]);
}

// ---------------- top-k(4 ways) sparsified softmax combine ----------------
__global__ __launch_bounds__(64) void topk_kernel(
    const float* __restrict__ attn_raw, const float* __restrict__ invq,
    const float* __restrict__ invk, const float* __restrict__ temp,
    const float* __restrict__ mix, float* __restrict__ Acomb)
{
    const int rowid = blockIdx.x;  // bh*48 + c
    const int c = rowid % 48, bh = rowid / 48, h = bh & 3, b = bh >> 2;
    const int lane = threadIdx.x;
    __shared__ float a[48];
    const float iq = invq[b * 192 + h * 48 + c] * temp[h];
    if (lane < 48)
        a[lane] = attn_raw[(size_t)bh * 2304 + c * 48 + lane] * iq * invk[b * 192 + h * 48 + lane];
    __syncthreads();
    const float av = (lane < 48) ? a[lane] : -INFINITY;
    int cnt_gt = 0, cnt_ge = 0;
    if (lane < 48) {
        for (int j = 0; j < 48; j++) { cnt_gt += (a[j] > av); cnt_ge += (a[j] >= av); }
    }
    const float m = wmax(av);
    const float p = (lane < 48) ? expf(av - m) : 0.f;
    float coeff = 0.f;
    const int kks[4] = {24, 32, 36, 38};
    #pragma unroll
    for (int i = 0; i < 4; i++) {
        const int kk = kks[i];
        float cand = (lane < 48 && cnt_gt < kk && cnt_ge >= kk) ? av : -INFINITY;
        cand = wmax(cand);
        const bool pass = (lane < 48) && (av >= cand);
        float z = wsum(pass ? p : 0.f);
        coeff += pass ? (mix[i] / z) : 0.f;
    }
    if (lane < 48) Acomb[(size_t)bh * 2304 + c * 48 + lane] = p * coeff;
}

// ---------------- attn_out (T-layout bf16 [b][n][192]) = Acomb @ v ----------------
__global__ __launch_bounds__(256) void attnv_kernel(
    const float* __restrict__ Acomb, const bf16* __restrict__ V,
    bf16* __restrict__ OT, int N)
{
    __shared__ float As[48][48];
    __shared__ float vs[48][64];
    __shared__ bf16 ot[64][48];
    const int b = blockIdx.z, h = blockIdx.y;
    const int n0 = blockIdx.x * 64;
    const float* Ap = Acomb + (size_t)(b * 4 + h) * 2304;
    for (int i = threadIdx.x; i < 2304; i += 256) As[i / 48][i % 48] = Ap[i];
    const bf16* Vb = V + ((size_t)b * 192 + h * 48) * N;
    for (int i = threadIdx.x; i < 3072; i += 256) {
        const int r = i >> 6, cn = i & 63;
        vs[r][cn] = tof(Vb[(size_t)r * N + n0 + cn]);
    }
    __syncthreads();
    const int nl = threadIdx.x & 63;
    const int cg = threadIdx.x >> 6;
    for (int c = cg * 12; c < cg * 12 + 12; c++) {
        float s = 0.f;
        #pragma unroll
        for (int d = 0; d < 48; d++) s += As[c][d] * vs[d][nl];
        ot[nl][c] = __float2bfloat16(s);
    }
    __syncthreads();
    for (int idx = threadIdx.x; idx < 384; idx += 256) {
        const int r = idx / 6, q = idx % 6;
        *(uint4*)((char*)&OT[((size_t)b * N + n0 + r) * 192 + h * 48] + q * 16) =
            *(uint4*)((char*)&ot[r][0] + q * 16);
    }
}

// ---------------- launch ----------------
extern "C" void kernel_launch(void* const* d_in, const int* in_sizes, int n_in,
                              void* d_out, int out_size, void* d_ws, size_t ws_size,
                              hipStream_t stream)
{
    const float* x       = (const float*)d_in[0];
    const float* y       = (const float*)d_in[1];
    const float* ln1_w   = (const float*)d_in[2];
    const float* ln1_b   = (const float*)d_in[3];
    const float* ln2_w   = (const float*)d_in[4];
    const float* ln2_b   = (const float*)d_in[5];
    const float* kv_w    = (const float*)d_in[6];
    const float* kv_dw   = (const float*)d_in[7];
    const float* q_w     = (const float*)d_in[8];
    const float* q_dw    = (const float*)d_in[9];
    const float* po_w    = (const float*)d_in[10];
    const float* temp    = (const float*)d_in[11];
    const float* mix     = (const float*)d_in[12];
    const float* ffn_in_w  = (const float*)d_in[13];
    const float* ffn_dw    = (const float*)d_in[14];
    const float* ffn_out_w = (const float*)d_in[15];
    float* out = (float*)d_out;

    const int N = 16384;
    const size_t TB = (size_t)4 * N * 192 * 2;   // 25,165,824 bytes

    char* ws = (char*)d_ws;
    bf16* XT0 = (bf16*)ws;                        // yn / xn / xn2 (T-layout)
    bf16* XT1 = (bf16*)(ws + TB);                 // q/k/v_pre then attn_outT
    bf16* Q   = (bf16*)(ws + 2 * TB);
    bf16* Kb  = (bf16*)(ws + 3 * TB);
    bf16* V   = (bf16*)(ws + 4 * TB);
    float* S  = (float*)(ws + 5 * TB);            // @ 125,829,120
    float* invq = S;
    float* invk = S + 768;
    float* attn_raw = S + 1536;
    float* Acomb = attn_raw + 16 * 48 * 48;       // S region < 310 KB
    // bf16 weights after S region
    bf16* Wq  = (bf16*)(ws + 5 * TB + 331776);
    bf16* Wkv = Wq + 36864;        // 384x192
    bf16* Wpo = Wkv + 73728;       // 192x192
    bf16* Wfi = Wpo + 36864;       // 1024x192 (1020 real + 4 zero rows)
    bf16* Wfo = Wfi + 196608;      // 192x512  (K padded 510->512)
    // FFN overlay (attention buffers dead): FB [2][1020][N] then GT [2][N][512]
    bf16* FB = (bf16*)(ws + TB);
    bf16* GT = (bf16*)(ws + TB + (size_t)66846720);   // ends at 125,566,976 < 5*TB

    const dim3 blk(256);
    const dim3 ln_grid(4 * N / 128);
    const dim3 dwg(8, 192, 4);
    const dim3 g192(3, N / 64, 4);

    // ---- preconvert weights to bf16 ----
    wconv_kernel<<<dim3((192 * 192 + 255) / 256), blk, 0, stream>>>(q_w, Wq, 192, 192, 192, 192, 192);
    wconv_kernel<<<dim3((384 * 192 + 255) / 256), blk, 0, stream>>>(kv_w, Wkv, 384, 384, 192, 192, 192);
    wconv_kernel<<<dim3((192 * 192 + 255) / 256), blk, 0, stream>>>(po_w, Wpo, 192, 192, 192, 192, 192);
    wconv_kernel<<<dim3((1024 * 192 + 255) / 256), blk, 0, stream>>>(ffn_in_w, Wfi, 1020, 1024, 192, 192, 192);
    wconv_kernel<<<dim3((192 * 512 + 255) / 256), blk, 0, stream>>>(ffn_out_w, Wfo, 192, 192, 510, 512, 510);

    // ---- q path ----
    ln_t_kernel<<<ln_grid, blk, 0, stream>>>(y, ln1_w, ln1_b, XT0, N);
    wreg_gemm_kernel<192, 64, bf16, false><<<g192, blk, 0, stream>>>(Wq, XT0, nullptr, XT1, 192, 192, N);
    dwconv3_tile_kernel<<<dwg, blk, 0, stream>>>(XT1, q_dw, Q, 192);
    // ---- k, v path ----
    ln_t_kernel<<<ln_grid, blk, 0, stream>>>(x, ln1_w, ln1_b, XT0, N);
    wreg_gemm_kernel<192, 64, bf16, false><<<g192, blk, 0, stream>>>(Wkv, XT0, nullptr, XT1, 192, 192, N);
    dwconv3_tile_kernel<<<dwg, blk, 0, stream>>>(XT1, kv_dw, Kb, 192);
    wreg_gemm_kernel<192, 64, bf16, false><<<g192, blk, 0, stream>>>(Wkv + 192 * 192, XT0, nullptr, XT1, 192, 192, N);
    dwconv3_tile_kernel<<<dwg, blk, 0, stream>>>(XT1, kv_dw + 192 * 9, V, 192);
    // ---- norms, attention matrix, combine ----
    rownorm_kernel<<<dim3(768), blk, 0, stream>>>(Q, invq, N);
    rownorm_kernel<<<dim3(768), blk, 0, stream>>>(Kb, invk, N);
    hipMemsetAsync(attn_raw, 0, 16 * 48 * 48 * 4, stream);
    gram_mfma_kernel<<<dim3(32, 4, 4), dim3(192), 0, stream>>>(Q, Kb, attn_raw, N);
    topk_kernel<<<dim3(768), dim3(64), 0, stream>>>(attn_raw, invq, invk, temp, mix, Acomb);
    // ---- attn_out (T) -> XT1 ; x1 = x + po(attn_out) -> out ----
    attnv_kernel<<<dim3(N / 64, 4, 4), blk, 0, stream>>>(Acomb, V, XT1, N);
    wreg_gemm_kernel<192, 64, float, true><<<g192, blk, 0, stream>>>(Wpo, XT1, x, out, 192, 192, N);
    // ---- FFN ----
    ln_t_kernel<<<ln_grid, blk, 0, stream>>>(out, ln2_w, ln2_b, XT0, N);
    for (int bp = 0; bp < 2; bp++) {
        const bf16* X2 = XT0 + (size_t)bp * 2 * N * 192;
        float* Ybp = out + (size_t)bp * 2 * 192 * N;
        wreg_gemm_kernel<192, 64, bf16, false><<<dim3(16, N / 64, 2), blk, 0, stream>>>(Wfi, X2, nullptr, FB, 1020, 192, N);
        dwgelu_tile_kernel<<<dim3(16, 128, 2), blk, 0, stream>>>(FB, ffn_dw, GT);
        wreg_gemm_kernel<512, 128, float, true><<<dim3(3, N / 128, 2), blk, 0, stream>>>(Wfo, GT, Ybp, Ybp, 192, 512, N);
    }
}

// Round 11
// 832.902 us; speedup vs baseline: 1.0698x; 1.0698x over previous
//
#include <hip/hip_runtime.h>
#include <hip/hip_bf16.h>

using bf16 = __hip_bfloat16;
typedef __attribute__((ext_vector_type(8))) short short8;
typedef __attribute__((ext_vector_type(4))) float f32x4;

// ---------------- helpers ----------------
__device__ __forceinline__ float tof(float v) { return v; }
__device__ __forceinline__ float tof(bf16 v) { return __bfloat162float(v); }
__device__ __forceinline__ float s2f(short s) {
    return __uint_as_float(((unsigned)(unsigned short)s) << 16);
}
__device__ __forceinline__ void storev(float* p, float v) { *p = v; }
__device__ __forceinline__ void storev(bf16* p, float v) { *p = __float2bfloat16(v); }
__device__ __forceinline__ short f2bf_bits(float v) {
    bf16 h = __float2bfloat16(v);
    return *(short*)&h;
}
__device__ __forceinline__ float wsum(float v) {
    #pragma unroll
    for (int o = 32; o > 0; o >>= 1) v += __shfl_xor(v, o);
    return v;
}
__device__ __forceinline__ float wmax(float v) {
    #pragma unroll
    for (int o = 32; o > 0; o >>= 1) v = fmaxf(v, __shfl_xor(v, o));
    return v;
}

// ---------------- weight preconvert: fp32 [Oreal][WLD] -> bf16 [Oalloc][KP], pad 0 ----
__global__ __launch_bounds__(256) void wconv_kernel(
    const float* __restrict__ src, bf16* __restrict__ dst,
    int Oreal, int Oalloc, int K, int KP, int WLD)
{
    const int idx = blockIdx.x * 256 + threadIdx.x;
    if (idx >= Oalloc * KP) return;
    const int o = idx / KP, k = idx % KP;
    float v = (o < Oreal && k < K) ? src[(size_t)o * WLD + k] : 0.f;
    dst[idx] = __float2bfloat16(v);
}

// ---------------- LayerNorm C=192: fp32 [b][192][N] -> bf16 [b][n][192] ----------------
__global__ __launch_bounds__(256) void ln_t_kernel(
    const float* __restrict__ X, const float* __restrict__ w,
    const float* __restrict__ bias, bf16* __restrict__ Y, int N)
{
    const int wv = threadIdx.x >> 6, ln_ = threadIdx.x & 63;
    const int p = blockIdx.x * 128 + wv * 32 + (ln_ & 31);   // flat pixel in B*N
    const int b = p >> 14, n = p & 16383;                    // N = 16384
    const int c0 = (ln_ >> 5) * 96;
    const float* xp = X + ((size_t)b * 192 + c0) * N + n;
    float s = 0.f, s2 = 0.f;
    #pragma unroll
    for (int c = 0; c < 96; c++) { float v = xp[(size_t)c * N]; s += v; s2 += v * v; }
    s += __shfl_xor(s, 32);
    s2 += __shfl_xor(s2, 32);
    const float mean = s * (1.f / 192.f);
    const float rstd = rsqrtf(s2 * (1.f / 192.f) - mean * mean + 1e-5f);
    bf16* yp = Y + ((size_t)(b * 16384 + n)) * 192 + c0;
    #pragma unroll
    for (int c = 0; c < 96; c += 2) {
        float v0 = (xp[(size_t)c * N] - mean) * rstd * w[c0 + c] + bias[c0 + c];
        float v1 = (xp[(size_t)(c + 1) * N] - mean) * rstd * w[c0 + c + 1] + bias[c0 + c + 1];
        unsigned u = (unsigned)(unsigned short)f2bf_bits(v0) |
                     ((unsigned)(unsigned short)f2bf_bits(v1) << 16);
        *(unsigned*)(yp + c) = u;
    }
}

// ---- weights-in-registers MFMA GEMM, XCD-swizzled: Y[b][o][n] = W[o][:].X[b][n][:] ----
// TEPI: bf16 output staged through LDS transpose -> coalesced short8 row stores.
template<int K, int NSTEP, typename YT, bool RESID, bool TEPI>
__global__ __launch_bounds__(256) void wreg_gemm_kernel(
    const bf16* __restrict__ Wb, const bf16* __restrict__ X,
    const float* __restrict__ Rsd, YT* __restrict__ Y,
    int O, int KS, int NROW)
{
    constexpr int KST = K / 32;
    __shared__ short ot[TEPI ? 64 : 1][TEPI ? 72 : 1];
    // bijective XCD swizzle: each XCD gets a contiguous work chunk, o fastest
    const int OT = gridDim.x, NT = gridDim.y;
    const int orig = blockIdx.x + OT * (blockIdx.y + NT * blockIdx.z);
    const int total = OT * NT * gridDim.z;
    const int qq = total >> 3, rr = total & 7;
    const int xcd = orig & 7, loc = orig >> 3;
    const int nw = (xcd < rr ? xcd * (qq + 1) : rr * (qq + 1) + (xcd - rr) * qq) + loc;
    const int o0 = (nw % OT) * 64;
    const int nbase = ((nw / OT) % NT) * NSTEP;
    const int b = nw / (OT * NT);

    const int wave = threadIdx.x >> 6, lane = threadIdx.x & 63;
    const int arow = lane & 15, kg = lane >> 4;

    short8 wf[KST];
    {
        const bf16* wp = Wb + (size_t)(o0 + wave * 16 + arow) * K + kg * 8;
        #pragma unroll
        for (int ks = 0; ks < KST; ks++) wf[ks] = *(const short8*)(wp + ks * 32);
    }
    const bf16* Xb = X + ((size_t)b * NROW + nbase) * KS;

    #pragma unroll 1
    for (int nt = 0; nt < NSTEP; nt += 64) {
        f32x4 acc[4];
        #pragma unroll
        for (int s = 0; s < 4; s++) acc[s] = (f32x4){0.f, 0.f, 0.f, 0.f};
        #pragma unroll
        for (int s = 0; s < 4; s++) {
            const bf16* xp = Xb + (size_t)(nt + s * 16 + arow) * KS + kg * 8;
            #pragma unroll
            for (int ks = 0; ks < KST; ks++) {
                short8 bfr = *(const short8*)(xp + ks * 32);
                acc[s] = __builtin_amdgcn_mfma_f32_16x16x32_bf16(wf[ks], bfr, acc[s], 0, 0, 0);
            }
        }
        if constexpr (TEPI) {
            __syncthreads();
            #pragma unroll
            for (int s = 0; s < 4; s++)
                #pragma unroll
                for (int r = 0; r < 4; r++)
                    ot[wave * 16 + kg * 4 + r][s * 16 + arow] = f2bf_bits(acc[s][r]);
            __syncthreads();
            for (int i = threadIdx.x; i < 512; i += 256) {
                const int row = i >> 3, c8 = (i & 7) * 8;
                const int o = o0 + row;
                if (o < O) {
                    short8 vv = *(const short8*)&ot[row][c8];
                    *(short8*)((bf16*)Y + ((size_t)b * O + o) * NROW + nbase + nt + c8) = vv;
                }
            }
        } else {
            #pragma unroll
            for (int s = 0; s < 4; s++) {
                #pragma unroll
                for (int r = 0; r < 4; r++) {
                    const int o = o0 + wave * 16 + kg * 4 + r;
                    if (o < O) {
                        const size_t off = ((size_t)b * O + o) * NROW + nbase + nt + s * 16 + arow;
                        float v = acc[s][r];
                        if (RESID) v += Rsd[off];
                        storev(&Y[off], v);
                    }
                }
            }
        }
    }
}

// -------- tiled depthwise 3x3 (bf16 planes), vector LDS reads: 1 ch x 16 y x 128 x ----
__global__ __launch_bounds__(256) void dwconv3_tile_kernel(
    const bf16* __restrict__ X, const float* __restrict__ Wd, bf16* __restrict__ Y,
    int CH)
{
    __shared__ short sm[18][144];   // x0 at col 8; zero halos at 7 and 136
    const int b = blockIdx.z, ch = blockIdx.y;
    const int y0 = blockIdx.x * 16;
    const int tid = threadIdx.x;
    const size_t base = ((size_t)b * CH + ch) * 16384;

    for (int idx = tid; idx < 288; idx += 256) {
        const int r = idx >> 4, xc = idx & 15;
        const int yy = y0 - 1 + r;
        short8 v = {0, 0, 0, 0, 0, 0, 0, 0};
        if (yy >= 0 && yy < 128) v = *(const short8*)(X + base + yy * 128 + xc * 8);
        *(short8*)&sm[r][8 + xc * 8] = v;
    }
    if (tid < 18) { sm[tid][7] = 0; sm[tid][136] = 0; }
    __syncthreads();

    float wv[9];
    #pragma unroll
    for (int i = 0; i < 9; i++) wv[i] = Wd[ch * 9 + i];

    const int ty = tid >> 4, xg = tid & 15;
    float a[8] = {0.f, 0.f, 0.f, 0.f, 0.f, 0.f, 0.f, 0.f};
    #pragma unroll
    for (int dy = 0; dy < 3; dy++) {
        const short* row = &sm[ty + dy][xg * 8];
        short8 pv = *(const short8*)row;
        short8 cv = *(const short8*)(row + 8);
        short8 nv = *(const short8*)(row + 16);
        float u[10];
        u[0] = s2f(((short*)&pv)[7]);
        #pragma unroll
        for (int j = 0; j < 8; j++) u[j + 1] = s2f(((short*)&cv)[j]);
        u[9] = s2f(((short*)&nv)[0]);
        const float wa = wv[dy * 3], wb = wv[dy * 3 + 1], wc = wv[dy * 3 + 2];
        #pragma unroll
        for (int j = 0; j < 8; j++) a[j] += wa * u[j] + wb * u[j + 1] + wc * u[j + 2];
    }
    short8 ov;
    #pragma unroll
    for (int j = 0; j < 8; j++) ((short*)&ov)[j] = f2bf_bits(a[j]);
    *(short8*)(Y + base + (size_t)(y0 + ty) * 128 + xg * 8) = ov;
}

// ---- tiled fused dw3(f1)->gelu * dw3(f2) -> GT[b][n][512] ; 4 hc x 8 y x 128 x ------
// FB layout [b][1020][N]: f1 plane = hc, f2 plane = 510 + hc.
__global__ __launch_bounds__(256) void dwgelu_tile_kernel(
    const bf16* __restrict__ FB, const float* __restrict__ Wd, bf16* __restrict__ GT)
{
    __shared__ short s1[4][10][144];
    __shared__ short s2[4][10][144];
    __shared__ short ot[4][8][136];
    const int b = blockIdx.z;
    const int y0 = blockIdx.x * 8;
    const int hc0 = blockIdx.y * 4;
    const int tid = threadIdx.x;

    for (int idx = tid; idx < 640; idx += 256) {
        const int c = idx / 160, rem = idx % 160;
        const int r = rem >> 4, xc = rem & 15;
        const int yy = y0 - 1 + r;
        const int hc = hc0 + c;
        short8 v1 = {0,0,0,0,0,0,0,0}, v2 = v1;
        if (hc < 510 && yy >= 0 && yy < 128) {
            const size_t sp = (size_t)yy * 128 + xc * 8;
            v1 = *(const short8*)(FB + ((size_t)b * 1020 + hc) * 16384 + sp);
            v2 = *(const short8*)(FB + ((size_t)b * 1020 + 510 + hc) * 16384 + sp);
        }
        *(short8*)&s1[c][r][8 + xc * 8] = v1;
        *(short8*)&s2[c][r][8 + xc * 8] = v2;
    }
    if (tid < 40) {
        const int c = tid / 10, r = tid % 10;
        s1[c][r][7] = 0; s1[c][r][136] = 0;
        s2[c][r][7] = 0; s2[c][r][136] = 0;
    }
    __syncthreads();

    const int c = tid >> 6, y2 = (tid >> 4) & 3, xg = tid & 15;
    const int hc = hc0 + c;
    float w1[9], w2[9];
    #pragma unroll
    for (int i = 0; i < 9; i++) {
        w1[i] = (hc < 510) ? Wd[(size_t)hc * 9 + i] : 0.f;
        w2[i] = (hc < 510) ? Wd[(size_t)(510 + hc) * 9 + i] : 0.f;
    }
    #pragma unroll
    for (int t = 0; t < 2; t++) {
        const int yy = y2 * 2 + t;
        float d1[8] = {0.f,0.f,0.f,0.f,0.f,0.f,0.f,0.f};
        float d2[8] = {0.f,0.f,0.f,0.f,0.f,0.f,0.f,0.f};
        #pragma unroll
        for (int dy = 0; dy < 3; dy++) {
            const short* r1 = &s1[c][yy + dy][xg * 8];
            const short* r2 = &s2[c][yy + dy][xg * 8];
            short8 pa = *(const short8*)r1;
            short8 ca = *(const short8*)(r1 + 8);
            short8 na = *(const short8*)(r1 + 16);
            short8 pb = *(const short8*)r2;
            short8 cb = *(const short8*)(r2 + 8);
            short8 nb = *(const short8*)(r2 + 16);
            float u[10], v[10];
            u[0] = s2f(((short*)&pa)[7]);
            v[0] = s2f(((short*)&pb)[7]);
            #pragma unroll
            for (int j = 0; j < 8; j++) {
                u[j + 1] = s2f(((short*)&ca)[j]);
                v[j + 1] = s2f(((short*)&cb)[j]);
            }
            u[9] = s2f(((short*)&na)[0]);
            v[9] = s2f(((short*)&nb)[0]);
            const float a0 = w1[dy * 3], a1 = w1[dy * 3 + 1], a2 = w1[dy * 3 + 2];
            const float b0 = w2[dy * 3], b1 = w2[dy * 3 + 1], b2 = w2[dy * 3 + 2];
            #pragma unroll
            for (int j = 0; j < 8; j++) {
                d1[j] += a0 * u[j] + a1 * u[j + 1] + a2 * u[j + 2];
                d2[j] += b0 * v[j] + b1 * v[j + 1] + b2 * v[j + 2];
            }
        }
        short8 ov;
        #pragma unroll
        for (int j = 0; j < 8; j++) {
            float g = 0.5f * d1[j] * (1.f + erff(d1[j] * 0.70710678118654752f)) * d2[j];
            ((short*)&ov)[j] = f2bf_bits(g);
        }
        *(short8*)&ot[c][yy][xg * 8] = ov;
    }
    __syncthreads();
    for (int idx = tid; idx < 1024; idx += 256) {
        const int row = idx >> 7, col = idx & 127;
        short v0 = ot[0][row][col], v1 = ot[1][row][col];
        short v2 = ot[2][row][col], v3 = ot[3][row][col];
        uint2 pk;
        pk.x = (unsigned)(unsigned short)v0 | ((unsigned)(unsigned short)v1 << 16);
        pk.y = (unsigned)(unsigned short)v2 | ((unsigned)(unsigned short)v3 << 16);
        *(uint2*)(GT + ((size_t)b * 16384 + y0 * 128 + idx) * 512 + hc0) = pk;
    }
}

// ---------------- row L2 norms (bf16 rows of length N), short8 loads ----------------
__global__ __launch_bounds__(256) void rownorm_kernel(
    const bf16* __restrict__ X, float* __restrict__ inv, int N)
{
    const int row = blockIdx.x;
    const bf16* p = X + (size_t)row * N;
    float s = 0.f;
    for (int i = threadIdx.x * 8; i < N; i += 2048) {
        short8 v = *(const short8*)(p + i);
        #pragma unroll
        for (int j = 0; j < 8; j++) { float f = s2f(((short*)&v)[j]); s += f * f; }
    }
    s = wsum(s);
    __shared__ float red[4];
    if ((threadIdx.x & 63) == 0) red[threadIdx.x >> 6] = s;
    __syncthreads();
    if (threadIdx.x == 0) {
        float t = red[0] + red[1] + red[2] + red[3];
        inv[row] = 1.f / fmaxf(sqrtf(t), 1e-12f);
    }
}

// ------- gram via MFMA: attn_raw[bh][c][d] += sum_n q[c,n]*k[d,n] over n-chunk --------
__global__ __launch_bounds__(192) void gram_mfma_kernel(
    const bf16* __restrict__ Q, const bf16* __restrict__ K,
    float* __restrict__ attn_raw, int N)
{
    const int b = blockIdx.z, h = blockIdx.y;
    const int n0base = blockIdx.x * 512;
    const int wave = threadIdx.x >> 6, lane = threadIdx.x & 63;
    const int arow = lane & 15, kg = lane >> 4;
    const bf16* Qb = Q + ((size_t)b * 192 + h * 48 + wave * 16 + arow) * N;
    const bf16* Kb = K + ((size_t)b * 192 + h * 48) * N;

    f32x4 acc[3];
    #pragma unroll
    for (int di = 0; di < 3; di++) acc[di] = (f32x4){0.f, 0.f, 0.f, 0.f};

    #pragma unroll 4
    for (int t = 0; t < 16; t++) {
        const int n0 = n0base + t * 32 + kg * 8;
        short8 a = *(const short8*)(Qb + n0);
        #pragma unroll
        for (int di = 0; di < 3; di++) {
            short8 bfr = *(const short8*)(Kb + (size_t)(di * 16 + arow) * N + n0);
            acc[di] = __builtin_amdgcn_mfma_f32_16x16x32_bf16(a, bfr, acc[di], 0, 0, 0);
        }
    }
    float* A = attn_raw + (size_t)(b * 4 + h) * 2304;
    const int c = wave * 16 + kg * 4;
    #pragma unroll
    for (int di = 0; di < 3; di++)
        #pragma unroll
        for (int r = 0; r < 4; r++)
            atomicAdd(&A[(c + r) * 48 + di * 16 + arow], acc[di][r]);
}

// ---------------- top-k(4 ways) sparsified softmax combine ----------------
__global__ __launch_bounds__(64) void topk_kernel(
    const float* __restrict__ attn_raw, const float* __restrict__ invq,
    const float* __restrict__ invk, const float* __restrict__ temp,
    const float* __restrict__ mix, float* __restrict__ Acomb)
{
    const int rowid = blockIdx.x;  // bh*48 + c
    const int c = rowid % 48, bh = rowid / 48, h = bh & 3, b = bh >> 2;
    const int lane = threadIdx.x;
    __shared__ float a[48];
    const float iq = invq[b * 192 + h * 48 + c] * temp[h];
    if (lane < 48)
        a[lane] = attn_raw[(size_t)bh * 2304 + c * 48 + lane] * iq * invk[b * 192 + h * 48 + lane];
    __syncthreads();
    const float av = (lane < 48) ? a[lane] : -INFINITY;
    int cnt_gt = 0, cnt_ge = 0;
    if (lane < 48) {
        for (int j = 0; j < 48; j++) { cnt_gt += (a[j] > av); cnt_ge += (a[j] >= av); }
    }
    const float m = wmax(av);
    const float p = (lane < 48) ? expf(av - m) : 0.f;
    float coeff = 0.f;
    const int kks[4] = {24, 32, 36, 38};
    #pragma unroll
    for (int i = 0; i < 4; i++) {
        const int kk = kks[i];
        float cand = (lane < 48 && cnt_gt < kk && cnt_ge >= kk) ? av : -INFINITY;
        cand = wmax(cand);
        const bool pass = (lane < 48) && (av >= cand);
        float z = wsum(pass ? p : 0.f);
        coeff += pass ? (mix[i] / z) : 0.f;
    }
    if (lane < 48) Acomb[(size_t)bh * 2304 + c * 48 + lane] = p * coeff;
}

// ---------------- attn_out (T-layout bf16 [b][n][192]) = Acomb @ v ----------------
__global__ __launch_bounds__(256) void attnv_kernel(
    const float* __restrict__ Acomb, const bf16* __restrict__ V,
    bf16* __restrict__ OT, int N)
{
    __shared__ float As[48][48];
    __shared__ float vs[48][64];
    __shared__ bf16 ot[64][48];
    const int b = blockIdx.z, h = blockIdx.y;
    const int n0 = blockIdx.x * 64;
    const float* Ap = Acomb + (size_t)(b * 4 + h) * 2304;
    for (int i = threadIdx.x; i < 2304; i += 256) As[i / 48][i % 48] = Ap[i];
    const bf16* Vb = V + ((size_t)b * 192 + h * 48) * N;
    for (int i = threadIdx.x; i < 3072; i += 256) {
        const int r = i >> 6, cn = i & 63;
        vs[r][cn] = tof(Vb[(size_t)r * N + n0 + cn]);
    }
    __syncthreads();
    const int nl = threadIdx.x & 63;
    const int cg = threadIdx.x >> 6;
    for (int c = cg * 12; c < cg * 12 + 12; c++) {
        float s = 0.f;
        #pragma unroll
        for (int d = 0; d < 48; d++) s += As[c][d] * vs[d][nl];
        ot[nl][c] = __float2bfloat16(s);
    }
    __syncthreads();
    for (int idx = threadIdx.x; idx < 384; idx += 256) {
        const int r = idx / 6, q = idx % 6;
        *(uint4*)((char*)&OT[((size_t)b * N + n0 + r) * 192 + h * 48] + q * 16) =
            *(uint4*)((char*)&ot[r][0] + q * 16);
    }
}

// ---------------- launch ----------------
extern "C" void kernel_launch(void* const* d_in, const int* in_sizes, int n_in,
                              void* d_out, int out_size, void* d_ws, size_t ws_size,
                              hipStream_t stream)
{
    const float* x       = (const float*)d_in[0];
    const float* y       = (const float*)d_in[1];
    const float* ln1_w   = (const float*)d_in[2];
    const float* ln1_b   = (const float*)d_in[3];
    const float* ln2_w   = (const float*)d_in[4];
    const float* ln2_b   = (const float*)d_in[5];
    const float* kv_w    = (const float*)d_in[6];
    const float* kv_dw   = (const float*)d_in[7];
    const float* q_w     = (const float*)d_in[8];
    const float* q_dw    = (const float*)d_in[9];
    const float* po_w    = (const float*)d_in[10];
    const float* temp    = (const float*)d_in[11];
    const float* mix     = (const float*)d_in[12];
    const float* ffn_in_w  = (const float*)d_in[13];
    const float* ffn_dw    = (const float*)d_in[14];
    const float* ffn_out_w = (const float*)d_in[15];
    float* out = (float*)d_out;

    const int N = 16384;
    const size_t TB = (size_t)4 * N * 192 * 2;   // 25,165,824 bytes

    char* ws = (char*)d_ws;
    bf16* XT0 = (bf16*)ws;                        // yn / xn / xn2 (T-layout)
    bf16* XT1 = (bf16*)(ws + TB);                 // q/k/v_pre then attn_outT
    bf16* Q   = (bf16*)(ws + 2 * TB);
    bf16* Kb  = (bf16*)(ws + 3 * TB);
    bf16* V   = (bf16*)(ws + 4 * TB);
    float* S  = (float*)(ws + 5 * TB);            // @ 125,829,120
    float* invq = S;
    float* invk = S + 768;
    float* attn_raw = S + 1536;
    float* Acomb = attn_raw + 16 * 48 * 48;       // S region < 310 KB
    // bf16 weights after S region
    bf16* Wq  = (bf16*)(ws + 5 * TB + 331776);
    bf16* Wkv = Wq + 36864;        // 384x192
    bf16* Wpo = Wkv + 73728;       // 192x192
    bf16* Wfi = Wpo + 36864;       // 1024x192 (1020 real + 4 zero rows)
    bf16* Wfo = Wfi + 196608;      // 192x512  (K padded 510->512)
    // FFN overlay (attention buffers dead): FB [2][1020][N] then GT [2][N][512]
    bf16* FB = (bf16*)(ws + TB);
    bf16* GT = (bf16*)(ws + TB + (size_t)66846720);   // ends at 125,566,976 < 5*TB

    const dim3 blk(256);
    const dim3 ln_grid(4 * N / 128);
    const dim3 dwg(8, 192, 4);
    const dim3 g192(3, N / 128, 4);

    // ---- preconvert weights to bf16 ----
    wconv_kernel<<<dim3((192 * 192 + 255) / 256), blk, 0, stream>>>(q_w, Wq, 192, 192, 192, 192, 192);
    wconv_kernel<<<dim3((384 * 192 + 255) / 256), blk, 0, stream>>>(kv_w, Wkv, 384, 384, 192, 192, 192);
    wconv_kernel<<<dim3((192 * 192 + 255) / 256), blk, 0, stream>>>(po_w, Wpo, 192, 192, 192, 192, 192);
    wconv_kernel<<<dim3((1024 * 192 + 255) / 256), blk, 0, stream>>>(ffn_in_w, Wfi, 1020, 1024, 192, 192, 192);
    wconv_kernel<<<dim3((192 * 512 + 255) / 256), blk, 0, stream>>>(ffn_out_w, Wfo, 192, 192, 510, 512, 510);

    // ---- q path ----
    ln_t_kernel<<<ln_grid, blk, 0, stream>>>(y, ln1_w, ln1_b, XT0, N);
    wreg_gemm_kernel<192, 128, bf16, false, true><<<g192, blk, 0, stream>>>(Wq, XT0, nullptr, XT1, 192, 192, N);
    dwconv3_tile_kernel<<<dwg, blk, 0, stream>>>(XT1, q_dw, Q, 192);
    // ---- k, v path ----
    ln_t_kernel<<<ln_grid, blk, 0, stream>>>(x, ln1_w, ln1_b, XT0, N);
    wreg_gemm_kernel<192, 128, bf16, false, true><<<g192, blk, 0, stream>>>(Wkv, XT0, nullptr, XT1, 192, 192, N);
    dwconv3_tile_kernel<<<dwg, blk, 0, stream>>>(XT1, kv_dw, Kb, 192);
    wreg_gemm_kernel<192, 128, bf16, false, true><<<g192, blk, 0, stream>>>(Wkv + 192 * 192, XT0, nullptr, XT1, 192, 192, N);
    dwconv3_tile_kernel<<<dwg, blk, 0, stream>>>(XT1, kv_dw + 192 * 9, V, 192);
    // ---- norms, attention matrix, combine ----
    rownorm_kernel<<<dim3(768), blk, 0, stream>>>(Q, invq, N);
    rownorm_kernel<<<dim3(768), blk, 0, stream>>>(Kb, invk, N);
    hipMemsetAsync(attn_raw, 0, 16 * 48 * 48 * 4, stream);
    gram_mfma_kernel<<<dim3(32, 4, 4), dim3(192), 0, stream>>>(Q, Kb, attn_raw, N);
    topk_kernel<<<dim3(768), dim3(64), 0, stream>>>(attn_raw, invq, invk, temp, mix, Acomb);
    // ---- attn_out (T) -> XT1 ; x1 = x + po(attn_out) -> out ----
    attnv_kernel<<<dim3(N / 64, 4, 4), blk, 0, stream>>>(Acomb, V, XT1, N);
    wreg_gemm_kernel<192, 128, float, true, false><<<g192, blk, 0, stream>>>(Wpo, XT1, x, out, 192, 192, N);
    // ---- FFN ----
    ln_t_kernel<<<ln_grid, blk, 0, stream>>>(out, ln2_w, ln2_b, XT0, N);
    for (int bp = 0; bp < 2; bp++) {
        const bf16* X2 = XT0 + (size_t)bp * 2 * N * 192;
        float* Ybp = out + (size_t)bp * 2 * 192 * N;
        wreg_gemm_kernel<192, 128, bf16, false, true><<<dim3(16, N / 128, 2), blk, 0, stream>>>(Wfi, X2, nullptr, FB, 1020, 192, N);
        dwgelu_tile_kernel<<<dim3(16, 128, 2), blk, 0, stream>>>(FB, ffn_dw, GT);
        wreg_gemm_kernel<512, 128, float, true, false><<<dim3(3, N / 128, 2), blk, 0, stream>>>(Wfo, GT, Ybp, Ybp, 192, 512, N);
    }
}